// Round 8
// baseline (180.431 us; speedup 1.0000x reference)
//
#include <hip/hip_runtime.h>

typedef __attribute__((ext_vector_type(8))) short bf16x8_t;
typedef __attribute__((ext_vector_type(4))) float f32x4_t;

#define AS1C(p) ((const __attribute__((address_space(1))) void*)(p))
#define AS3(p)  ((__attribute__((address_space(3))) void*)(p))

#define N_HEAD 12
#define SEQ_T 1024
#define CDIM 768
#define HDIM 64
#define L2E 1.44269504f

__device__ __forceinline__ unsigned short f2bf(float f) {
    union { float f; unsigned int u; } v;
    v.f = f;
    unsigned int r = (v.u + 0x7fffu + ((v.u >> 16) & 1u)) >> 16;
    return (unsigned short)r;
}

// HW packed fp32->bf16 (RNE on gfx950) — 1 instr replaces ~10 bit-ops per pair.
__device__ __forceinline__ unsigned int cvt_pk_bf16(float a, float b) {
    unsigned int r;
    asm("v_cvt_pk_bf16_f32 %0, %1, %2" : "=v"(r) : "v"(a), "v"(b));
    return r;
}

// Fused prep: [0,6144) cvt x fp32->bf16; [6144,7872) transpose w_attn; [7872,8448) w_proj.
__global__ __launch_bounds__(256) void prep(
    const float4* __restrict__ x4, ushort4* __restrict__ xbf4,
    const float* __restrict__ w_attn, unsigned short* __restrict__ waT,
    const float* __restrict__ w_proj, unsigned short* __restrict__ wpT)
{
    __shared__ float tile[32][33];
    const int blk = blockIdx.x;
    const int tid = threadIdx.x;
    if (blk < 6144) {
        int i = blk * 256 + tid;
        float4 v = x4[i];
        uint2 o;
        o.x = cvt_pk_bf16(v.x, v.y);
        o.y = cvt_pk_bf16(v.z, v.w);
        *(uint2*)&xbf4[i] = o;
        return;
    }
    const float* src; unsigned short* dst; int R, Cc, c0, r0;
    if (blk < 7872) {
        int idx = blk - 6144;           // w_attn: tiles (72 c, 24 r)
        src = w_attn; dst = waT; R = 768; Cc = 2304;
        c0 = (idx % 72) * 32; r0 = (idx / 72) * 32;
    } else {
        int idx = blk - 7872;           // w_proj: tiles (24 c, 24 r)
        src = w_proj; dst = wpT; R = 768; Cc = 768;
        c0 = (idx % 24) * 32; r0 = (idx / 24) * 32;
    }
    const int tx = tid & 31, ty = tid >> 5;
#pragma unroll
    for (int i = 0; i < 4; i++)
        tile[ty + i * 8][tx] = src[(size_t)(r0 + ty + i * 8) * Cc + c0 + tx];
    __syncthreads();
#pragma unroll
    for (int i = 0; i < 4; i++)
        dst[(size_t)(c0 + ty + i * 8) * R + r0 + tx] = f2bf(tile[tx][ty + i * 8]);
}

// ---------------------------------------------------------------------------
// qkv core R8: BM=128 x BN=256, BK=32, 8 waves (2M x 4N, 64x64 per wave).
// Rationale: qkv is staged-bytes-rate-bound (~13.3 B/cyc/CU across all prior
// schedule variants). 128x256 cuts staged bytes 450 -> 337 MB (B re-staged
// 64x either way, A 18 -> 9... A x9 + B x64). BK=32 keeps dbuf LDS at 48 KB
// (2-3 blocks/CU). Same 2-phase stage-then-compute + __syncthreads structure
// as the 55-us champion; K-order kt*32 ascending == champion's accumulation
// order (bitwise-identical output). BK=32 rows are 64 B -> ~4-way ds_read
// bank conflict (1.58x, tolerable: ds_read not the binding pipe).
// ---------------------------------------------------------------------------
__device__ __forceinline__ void stage_qkv(
    const unsigned short* __restrict__ A, const unsigned short* __restrict__ Bt,
    unsigned short* As, unsigned short* Bs, int mBase, int nBase, int kt,
    int wv, int lane)
{
    {   // A tile: 128 rows x 4 granules = 512 chunks; 512 thr -> 1 chunk
        int cbase = wv * 64;
        int ci = cbase + lane;
        int r = ci >> 2;                      // 0..127
        int g = (ci & 3) ^ (r & 3);           // swizzled source granule
        __builtin_amdgcn_global_load_lds(
            AS1C(A + (size_t)(mBase + r) * 768 + kt + g * 8),
            AS3(As + cbase * 8), 16, 0, 0);
    }
#pragma unroll
    for (int i = 0; i < 2; i++) {             // B tile: 256 rows x 4 = 1024 chunks
        int cbase = i * 512 + wv * 64;
        int ci = cbase + lane;
        int r = ci >> 2;                      // 0..255
        int g = (ci & 3) ^ (r & 3);
        __builtin_amdgcn_global_load_lds(
            AS1C(Bt + (size_t)(nBase + r) * 768 + kt + g * 8),
            AS3(Bs + cbase * 8), 16, 0, 0);
    }
}   // 3 global_load_lds per thread per K-step

// GEMM1: qkv = x @ w_attn + b_attn. Grid 576 (576%8==0, XCD-sliced), 512 thr.
__global__ __launch_bounds__(512) void gemm_qkv(
    const unsigned short* __restrict__ x, const unsigned short* __restrict__ waT,
    const float* __restrict__ b_attn,
    unsigned short* __restrict__ qbuf, unsigned short* __restrict__ kbuf,
    unsigned short* __restrict__ vbuf)
{
    __shared__ __align__(16) unsigned short As[2][128 * 32];   // 16 KB
    __shared__ __align__(16) unsigned short Bs[2][256 * 32];   // 32 KB
    const int lid = blockIdx.x;
    const int xcd = lid & 7;
    const int j = lid >> 3;                 // 0..71
    const int mTile = xcd * 8 + (j & 7);    // 0..63
    const int nTile = j >> 3;               // 0..8
    const int mBase = mTile * 128;
    const int nBase = nTile * 256;

    const int tid  = threadIdx.x;
    const int lane = tid & 63;
    const int wv   = tid >> 6;              // 0..7
    const int quad = lane >> 4;
    const int l16  = lane & 15;
    const int wm   = (wv >> 2) * 64;        // 2 M-waves
    const int wn   = (wv & 3) * 64;         // 4 N-waves

    f32x4_t zero = {0.f, 0.f, 0.f, 0.f};
    f32x4_t acc[4][4];
#pragma unroll
    for (int tm = 0; tm < 4; tm++)
#pragma unroll
        for (int tn = 0; tn < 4; tn++)
            acc[tm][tn] = zero;

    stage_qkv(x, waT, As[0], Bs[0], mBase, nBase, 0, wv, lane);
    __syncthreads();                         // tile0 resident

    const int rg = (quad ^ (l16 & 3)) << 3;  // swizzled read granule (row&3 == l16&3)
    for (int kt = 0; kt < 24; kt++) {
        const int cur = kt & 1;
        if (kt < 23)                          // stage t+1 first: latency overlaps compute
            stage_qkv(x, waT, As[cur ^ 1], Bs[cur ^ 1], mBase, nBase,
                      (kt + 1) * 32, wv, lane);
        __asm__ __volatile__("" ::: "memory");
        const unsigned short* Ac = As[cur];
        const unsigned short* Bc = Bs[cur];
        bf16x8_t af[4], bfv[4];
#pragma unroll
        for (int tm = 0; tm < 4; tm++)
            af[tm] = *(const bf16x8_t*)(Ac + (wm + tm * 16 + l16) * 32 + rg);
#pragma unroll
        for (int tn = 0; tn < 4; tn++)
            bfv[tn] = *(const bf16x8_t*)(Bc + (wn + tn * 16 + l16) * 32 + rg);
#pragma unroll
        for (int tm = 0; tm < 4; tm++)
#pragma unroll
            for (int tn = 0; tn < 4; tn++)
                acc[tm][tn] = __builtin_amdgcn_mfma_f32_16x16x32_bf16(
                    af[tm], bfv[tn], acc[tm][tn], 0, 0, 0);
        __syncthreads();   // drains stage (vmcnt 0) + WAR fence
    }

    const int part = nTile / 3;             // 0=q 1=k 2=v (block-uniform)
#pragma unroll
    for (int tn = 0; tn < 4; tn++) {
        int n = nBase + wn + tn * 16 + l16;     // 0..2303
        float bv = b_attn[n];
        int f = n - part * 768;
        int hh = f >> 6, d = f & 63;
        if (part == 2) {
#pragma unroll
            for (int tm = 0; tm < 4; tm++) {
                int t0 = mBase + wm + tm * 16 + quad * 4;   // 4-aligned, no b-crossing
                int bb = t0 >> 10, tt = t0 & 1023;
                uint2 pk2;
                pk2.x = cvt_pk_bf16(acc[tm][tn][0] + bv, acc[tm][tn][1] + bv);
                pk2.y = cvt_pk_bf16(acc[tm][tn][2] + bv, acc[tm][tn][3] + bv);
                *(uint2*)(vbuf + ((size_t)(bb * N_HEAD + hh) * HDIM + d) * SEQ_T + tt) = pk2;
            }
        } else {
            const float scale = (part == 0) ? L2E : 1.f;
            unsigned short* dst = (part == 0) ? qbuf : kbuf;
#pragma unroll
            for (int tm = 0; tm < 4; tm++) {
#pragma unroll
                for (int i = 0; i < 4; i++) {
                    int row = mBase + wm + tm * 16 + quad * 4 + i;
                    int bb = row >> 10, tt = row & 1023;
                    dst[((size_t)(bb * N_HEAD + hh) * SEQ_T + tt) * HDIM + d] =
                        f2bf((acc[tm][tn][i] + bv) * scale);
                }
            }
        }
    }
}

// ---------------------------------------------------------------------------
// proj core (R5-verified): 8-wave 128x256 tile, triple-buffered LDS (144 KB),
// depth-2 prefetch, counted vmcnt across raw s_barrier. proj-only.
// ---------------------------------------------------------------------------
#define KTILES 12               // 768 / 64
#define ASTRIDE (128 * 64)      // halfwords per A K-tile buffer
#define BSTRIDE (256 * 64)      // halfwords per B K-tile buffer

__device__ __forceinline__ void stage_tile(
    const unsigned short* __restrict__ A, const unsigned short* __restrict__ Bt,
    unsigned short* As, unsigned short* Bs, int mBase, int nBase, int kt,
    int wv, int lane)
{
#pragma unroll
    for (int i = 0; i < 2; i++) {
        int cbase = i * 512 + wv * 64;       // wave-uniform chunk base
        int ci = cbase + lane;
        int r = ci >> 3;
        int koff = (((ci & 7) ^ (r & 7)) << 3);
        __builtin_amdgcn_global_load_lds(
            AS1C(A + (size_t)(mBase + r) * 768 + kt + koff),
            AS3(As + cbase * 8), 16, 0, 0);
    }
#pragma unroll
    for (int i = 0; i < 4; i++) {
        int cbase = i * 512 + wv * 64;
        int ci = cbase + lane;
        int r = ci >> 3;
        int koff = (((ci & 7) ^ (r & 7)) << 3);
        __builtin_amdgcn_global_load_lds(
            AS1C(Bt + (size_t)(nBase + r) * 768 + kt + koff),
            AS3(Bs + cbase * 8), 16, 0, 0);
    }
}   // 6 global_load_lds per thread per K-tile

__device__ __forceinline__ void compute_tile(
    const unsigned short* As, const unsigned short* Bs,
    f32x4_t acc[4][4], int wm, int wn, int quad, int l16)
{
#pragma unroll
    for (int ks = 0; ks < 2; ks++) {
        bf16x8_t af[4], bfv[4];
#pragma unroll
        for (int tm = 0; tm < 4; tm++)
            af[tm] = *(const bf16x8_t*)(As + (wm + tm * 16 + l16) * 64 +
                                        (((ks * 4 + quad) ^ (l16 & 7)) << 3));
#pragma unroll
        for (int tn = 0; tn < 4; tn++)
            bfv[tn] = *(const bf16x8_t*)(Bs + (wn + tn * 16 + l16) * 64 +
                                         (((ks * 4 + quad) ^ (l16 & 7)) << 3));
#pragma unroll
        for (int tm = 0; tm < 4; tm++)
#pragma unroll
            for (int tn = 0; tn < 4; tn++)
                acc[tm][tn] = __builtin_amdgcn_mfma_f32_16x16x32_bf16(
                    af[tm], bfv[tn], acc[tm][tn], 0, 0, 0);
    }
}

__device__ __forceinline__ void gemm_core8(
    const unsigned short* __restrict__ A, const unsigned short* __restrict__ Bt,
    unsigned short* As, unsigned short* Bs, f32x4_t acc[4][4],
    int mBase, int nBase)
{
    const int tid  = threadIdx.x;
    const int lane = tid & 63;
    const int wv   = tid >> 6;          // 0..7
    const int quad = lane >> 4;
    const int l16  = lane & 15;
    const int wm   = (wv >> 2) * 64;    // 2 M-waves
    const int wn   = (wv & 3) * 64;     // 4 N-waves

    f32x4_t zero = {0.f, 0.f, 0.f, 0.f};
#pragma unroll
    for (int tm = 0; tm < 4; tm++)
#pragma unroll
        for (int tn = 0; tn < 4; tn++)
            acc[tm][tn] = zero;

    stage_tile(A, Bt, As + 0 * ASTRIDE, Bs + 0 * BSTRIDE, mBase, nBase, 0, wv, lane);
    stage_tile(A, Bt, As + 1 * ASTRIDE, Bs + 1 * BSTRIDE, mBase, nBase, 64, wv, lane);

#pragma unroll
    for (int t = 0; t < KTILES; t++) {
        if (t + 2 < KTILES) {
            const int nb = (t + 2) % 3;
            stage_tile(A, Bt, As + nb * ASTRIDE, Bs + nb * BSTRIDE,
                       mBase, nBase, (t + 2) * 64, wv, lane);
        }
        if (t + 2 < KTILES)
            asm volatile("s_waitcnt vmcnt(12)" ::: "memory");
        else if (t + 1 < KTILES)
            asm volatile("s_waitcnt vmcnt(6)" ::: "memory");
        else
            asm volatile("s_waitcnt vmcnt(0)" ::: "memory");
        __builtin_amdgcn_s_barrier();           // raw barrier: no vmcnt drain
        asm volatile("" ::: "memory");
        const int cb = t % 3;
        compute_tile(As + cb * ASTRIDE, Bs + cb * BSTRIDE, acc, wm, wn, quad, l16);
        asm volatile("" ::: "memory");
        __builtin_amdgcn_s_barrier();           // all waves done reading buf t%3
    }
}

// mask + exp2 + l-accumulate + pack to bf16 pairs (pure VALU, no memory ops).
__device__ __forceinline__ void mask_exp_pack(
    f32x4_t s[4], int diag, int qloc, int quad,
    float& lsum, unsigned int u[4][2])
{
    if (diag) {
#pragma unroll
        for (int c = 0; c < 4; c++)
#pragma unroll
            for (int i = 0; i < 4; i++)
                if (c * 16 + quad * 4 + i > qloc) s[c][i] = -1e30f;
    }
    float p[4][4];
#pragma unroll
    for (int c = 0; c < 4; c++)
#pragma unroll
        for (int i = 0; i < 4; i++)
            p[c][i] = __builtin_amdgcn_exp2f(s[c][i]);
#pragma unroll
    for (int c = 0; c < 4; c++)
        lsum += (p[c][0] + p[c][1]) + (p[c][2] + p[c][3]);
#pragma unroll
    for (int c = 0; c < 4; c++)
#pragma unroll
        for (int i2 = 0; i2 < 2; i2++)
            u[c][i2] = cvt_pk_bf16(p[c][2 * i2], p[c][2 * i2 + 1]);
}

__device__ __forceinline__ void p_write(
    unsigned short* pw, const unsigned int u[4][2], int quad, int l16)
{
#pragma unroll
    for (int c = 0; c < 4; c++)
#pragma unroll
        for (int i2 = 0; i2 < 2; i2++) {
            int g = c * 2 + (quad >> 1);
            *(unsigned int*)(pw + l16 * 64 + ((g ^ (l16 & 7)) << 3) +
                             4 * (quad & 1) + 2 * i2) = u[c][i2];
        }
}

// Fused causal attention. R8: dual Psh (separate P_B / P_A buffers) removes
// the A-write-after-B-read serialization on the shared per-wave buffer.
__global__ __launch_bounds__(256, 3) void attn_fused(
    const unsigned short* __restrict__ qb, const unsigned short* __restrict__ kb,
    const unsigned short* __restrict__ vb, unsigned short* __restrict__ attb)
{
    __shared__ __align__(16) unsigned short Kbuf[2][64 * 64];
    __shared__ __align__(16) unsigned short Vbuf[2][64 * 64];   // V^T tiles [d][s]
    __shared__ __align__(16) unsigned short Psh[8][16 * 64];    // [0..3]=B, [4..7]=A

    const int bhx = blockIdx.x;     // 0..95
    const int t   = blockIdx.y;     // 0..7; tiles t and 15-t
    const int h = bhx % N_HEAD;
    const int b = bhx / N_HEAD;
    const int tid = threadIdx.x;
    const int lane = tid & 63, wv = tid >> 6;
    const int quad = lane >> 4, l16 = lane & 15;
    const int tB = 15 - t, kmax = 15 - t;
    const int qloc = wv * 16 + l16;

    const size_t bh = (size_t)(b * N_HEAD + h);
    const unsigned short* kbase = kb + bh * SEQ_T * HDIM;
    const unsigned short* vbase = vb + bh * HDIM * SEQ_T;
    const unsigned short* qpt   = qb + bh * SEQ_T * HDIM;

    const int j0 = wv * 128 + lane, j1 = j0 + 64;
    const int r0 = j0 >> 3, g0 = (j0 & 7) ^ (r0 & 7);
    const int r1 = j1 >> 3, g1 = (j1 & 7) ^ (r1 & 7);
    const int rgK0 = r0 * 64 + g0 * 8,   rgK1 = r1 * 64 + g1 * 8;
    const int rgV0 = r0 * 1024 + g0 * 8, rgV1 = r1 * 1024 + g1 * 8;
    const int ldsc0 = (wv * 128) * 8, ldsc1 = (wv * 128 + 64) * 8;  // wave-uniform

    bf16x8_t qfA[2], qfB[2];
    {
        const unsigned short* qa  = qpt + (size_t)(t * 64 + qloc) * HDIM;
        const unsigned short* qbp = qpt + (size_t)(tB * 64 + qloc) * HDIM;
#pragma unroll
        for (int kc = 0; kc < 2; kc++) {
            qfA[kc] = *(const bf16x8_t*)(qa + kc * 32 + quad * 8);
            qfB[kc] = *(const bf16x8_t*)(qbp + kc * 32 + quad * 8);
        }
    }

    f32x4_t zero = {0.f, 0.f, 0.f, 0.f};
    f32x4_t oA[4], oB[4];
#pragma unroll
    for (int c = 0; c < 4; c++) { oA[c] = zero; oB[c] = zero; }
    float lA = 0.f, lB = 0.f;

    __builtin_amdgcn_global_load_lds(AS1C(kbase + rgK0), AS3(&Kbuf[0][0] + ldsc0), 16, 0, 0);
    __builtin_amdgcn_global_load_lds(AS1C(kbase + rgK1), AS3(&Kbuf[0][0] + ldsc1), 16, 0, 0);
    __builtin_amdgcn_global_load_lds(AS1C(vbase + rgV0), AS3(&Vbuf[0][0] + ldsc0), 16, 0, 0);
    __builtin_amdgcn_global_load_lds(AS1C(vbase + rgV1), AS3(&Vbuf[0][0] + ldsc1), 16, 0, 0);
    __syncthreads();

    for (int kt = 0; kt <= kmax; kt++) {
        const int cur = kt & 1, nxt = cur ^ 1;
        if (kt < kmax) {
            const unsigned short* kp = kbase + (kt + 1) * 4096;
            const unsigned short* vp = vbase + (kt + 1) * 64;
            __builtin_amdgcn_global_load_lds(AS1C(kp + rgK0), AS3(&Kbuf[nxt][0] + ldsc0), 16, 0, 0);
            __builtin_amdgcn_global_load_lds(AS1C(kp + rgK1), AS3(&Kbuf[nxt][0] + ldsc1), 16, 0, 0);
            __builtin_amdgcn_global_load_lds(AS1C(vp + rgV0), AS3(&Vbuf[nxt][0] + ldsc0), 16, 0, 0);
            __builtin_amdgcn_global_load_lds(AS1C(vp + rgV1), AS3(&Vbuf[nxt][0] + ldsc1), 16, 0, 0);
        }

        const unsigned short* Kc = &Kbuf[cur][0];
        const unsigned short* Vc = &Vbuf[cur][0];
        const int doA = (kt <= t);

        bf16x8_t vf[4][2];
#pragma unroll
        for (int nc = 0; nc < 4; nc++)
#pragma unroll
            for (int kc = 0; kc < 2; kc++)
                vf[nc][kc] = *(const bf16x8_t*)(Vc + (nc * 16 + l16) * 64 +
                                                (((kc * 4 + quad) ^ (l16 & 7)) << 3));

        f32x4_t sB[4], sA[4];
#pragma unroll
        for (int c = 0; c < 4; c++) {
            bf16x8_t kf0 = *(const bf16x8_t*)(Kc + (c * 16 + l16) * 64 +
                                              ((quad ^ (l16 & 7)) << 3));
            bf16x8_t kf1 = *(const bf16x8_t*)(Kc + (c * 16 + l16) * 64 +
                                              (((4 + quad) ^ (l16 & 7)) << 3));
            sB[c] = __builtin_amdgcn_mfma_f32_16x16x32_bf16(kf0, qfB[0], zero, 0, 0, 0);
            sB[c] = __builtin_amdgcn_mfma_f32_16x16x32_bf16(kf1, qfB[1], sB[c], 0, 0, 0);
            if (doA) {
                sA[c] = __builtin_amdgcn_mfma_f32_16x16x32_bf16(kf0, qfA[0], zero, 0, 0, 0);
                sA[c] = __builtin_amdgcn_mfma_f32_16x16x32_bf16(kf1, qfA[1], sA[c], 0, 0, 0);
            }
        }

        unsigned short* pwB = &Psh[wv][0];
        unsigned short* pwA = &Psh[4 + wv][0];
        unsigned int uB[4][2], uA[4][2];

        mask_exp_pack(sB, kt == tB, qloc, quad, lB, uB);
        __asm__ __volatile__("" ::: "memory");
        p_write(pwB, uB, quad, l16);                   // P_B -> LDS (own buffer)
        if (doA) {
            mask_exp_pack(sA, kt == t, qloc, quad, lA, uA);
            p_write(pwA, uA, quad, l16);               // P_A -> LDS (independent buffer)
        }
        __asm__ __volatile__("" ::: "memory");
        bf16x8_t pfB[2];
#pragma unroll
        for (int kc = 0; kc < 2; kc++)
            pfB[kc] = *(const bf16x8_t*)(pwB + l16 * 64 + (((kc * 4 + quad) ^ (l16 & 7)) << 3));
#pragma unroll
        for (int kc = 0; kc < 2; kc++)
#pragma unroll
            for (int nc = 0; nc < 4; nc++)
                oB[nc] = __builtin_amdgcn_mfma_f32_16x16x32_bf16(pfB[kc], vf[nc][kc], oB[nc], 0, 0, 0);
        if (doA) {
            bf16x8_t pfA[2];
#pragma unroll
            for (int kc = 0; kc < 2; kc++)
                pfA[kc] = *(const bf16x8_t*)(pwA + l16 * 64 + (((kc * 4 + quad) ^ (l16 & 7)) << 3));
#pragma unroll
            for (int kc = 0; kc < 2; kc++)
#pragma unroll
                for (int nc = 0; nc < 4; nc++)
                    oA[nc] = __builtin_amdgcn_mfma_f32_16x16x32_bf16(pfA[kc], vf[nc][kc], oA[nc], 0, 0, 0);
        }
        __syncthreads();
    }

    lA += __shfl_xor(lA, 16); lA += __shfl_xor(lA, 32);
    lB += __shfl_xor(lB, 16); lB += __shfl_xor(lB, 32);
    float invA = 1.f / lA, invB = 1.f / lB;
    float iA[4], iB[4];
#pragma unroll
    for (int i = 0; i < 4; i++) {
        iA[i] = __shfl(invA, quad * 4 + i);
        iB[i] = __shfl(invB, quad * 4 + i);
    }

#pragma unroll
    for (int nc = 0; nc < 4; nc++)
#pragma unroll
        for (int i = 0; i < 4; i++) {
            int rowA = t * 64 + wv * 16 + quad * 4 + i;
            int rowB = tB * 64 + wv * 16 + quad * 4 + i;
            int col = h * HDIM + nc * 16 + l16;
            attb[((size_t)b * SEQ_T + rowA) * CDIM + col] = f2bf(oA[nc][i] * iA[i]);
            attb[((size_t)b * SEQ_T + rowB) * CDIM + col] = f2bf(oB[nc][i] * iB[i]);
        }
}

// GEMM2: out(fp32) = att @ w_proj + b_proj. R5-verified config: BM=128 BN=256
// -> grid 64*3=192 (192%8==0, XCD-sliced), 512 thr, 144 KB LDS triple-buffer.
__global__ __launch_bounds__(512) void gemm_proj(
    const unsigned short* __restrict__ attb, const unsigned short* __restrict__ wpT,
    const float* __restrict__ b_proj, float* __restrict__ out)
{
    __shared__ __align__(16) unsigned short As[3 * ASTRIDE];   // 48 KB
    __shared__ __align__(16) unsigned short Bs[3 * BSTRIDE];   // 96 KB
    f32x4_t acc[4][4];
    const int lid = blockIdx.x;             // 0..191
    const int xcd = lid & 7;
    const int j = lid >> 3;                 // 0..23
    const int mTile = xcd * 8 + (j & 7);    // 0..63
    const int nTile = j >> 3;               // 0..2
    const int mBase = mTile * 128;
    const int nBase = nTile * 256;
    gemm_core8(attb, wpT, As, Bs, acc, mBase, nBase);

    const int tid  = threadIdx.x;
    const int lane = tid & 63;
    const int wv   = tid >> 6;
    const int quad = lane >> 4;
    const int l16  = lane & 15;
    const int wm   = (wv >> 2) * 64;
    const int wn   = (wv & 3) * 64;

#pragma unroll
    for (int tn = 0; tn < 4; tn++) {
        int n = nBase + wn + tn * 16 + l16;
        float bv = b_proj[n];
#pragma unroll
        for (int tm = 0; tm < 4; tm++)
#pragma unroll
            for (int i = 0; i < 4; i++) {
                int row = mBase + wm + tm * 16 + quad * 4 + i;
                out[(size_t)row * CDIM + n] = acc[tm][tn][i] + bv;
            }
    }
}

extern "C" void kernel_launch(void* const* d_in, const int* in_sizes, int n_in,
                              void* d_out, int out_size, void* d_ws, size_t ws_size,
                              hipStream_t stream) {
    const float* x      = (const float*)d_in[0];  // [8,1024,768] fp32
    const float* w_attn = (const float*)d_in[1];  // [768,2304]   fp32
    const float* b_attn = (const float*)d_in[2];  // [2304]       fp32
    const float* w_proj = (const float*)d_in[3];  // [768,768]    fp32
    const float* b_proj = (const float*)d_in[4];  // [768]        fp32
    float* out = (float*)d_out;                   // [8,1024,768] fp32

    unsigned short* ws   = (unsigned short*)d_ws;
    unsigned short* waT  = ws;                    // [2304][768] bf16
    unsigned short* wpT  = waT + 1769472;         // [768][768]  bf16
    unsigned short* xbf  = wpT + 589824;          // [8192][768] bf16
    unsigned short* qbuf = xbf + 6291456;         // [B,H,T,D] (log2e-scaled)
    unsigned short* kbuf = qbuf + 6291456;        // [B,H,T,D]
    unsigned short* vbuf = kbuf + 6291456;        // [B,H,D,T]
    unsigned short* attb = vbuf + 6291456;        // [B,T,C]
    // ws use: 67,633,152 bytes

    prep<<<dim3(8448), 256, 0, stream>>>((const float4*)x, (ushort4*)xbf,
                                         w_attn, waT, w_proj, wpT);
    gemm_qkv<<<dim3(576), 512, 0, stream>>>(xbf, waT, b_attn, qbuf, kbuf, vbuf);
    attn_fused<<<dim3(96, 8), 256, 0, stream>>>(qbuf, kbuf, vbuf, attb);
    gemm_proj<<<dim3(192), 512, 0, stream>>>(attb, wpT, b_proj, out);
}

// Round 9
// 172.701 us; speedup vs baseline: 1.0448x; 1.0448x over previous
//
#include <hip/hip_runtime.h>

typedef __attribute__((ext_vector_type(8))) short bf16x8_t;
typedef __attribute__((ext_vector_type(4))) float f32x4_t;

#define AS1C(p) ((const __attribute__((address_space(1))) void*)(p))
#define AS3(p)  ((__attribute__((address_space(3))) void*)(p))

#define N_HEAD 12
#define SEQ_T 1024
#define CDIM 768
#define HDIM 64
#define L2E 1.44269504f

__device__ __forceinline__ unsigned short f2bf(float f) {
    union { float f; unsigned int u; } v;
    v.f = f;
    unsigned int r = (v.u + 0x7fffu + ((v.u >> 16) & 1u)) >> 16;
    return (unsigned short)r;
}

// HW packed fp32->bf16 (RNE on gfx950) — 1 instr replaces ~10 bit-ops per pair.
__device__ __forceinline__ unsigned int cvt_pk_bf16(float a, float b) {
    unsigned int r;
    asm("v_cvt_pk_bf16_f32 %0, %1, %2" : "=v"(r) : "v"(a), "v"(b));
    return r;
}

// Fused prep: [0,6144) cvt x fp32->bf16; [6144,7872) transpose w_attn; [7872,8448) w_proj.
__global__ __launch_bounds__(256) void prep(
    const float4* __restrict__ x4, ushort4* __restrict__ xbf4,
    const float* __restrict__ w_attn, unsigned short* __restrict__ waT,
    const float* __restrict__ w_proj, unsigned short* __restrict__ wpT)
{
    __shared__ float tile[32][33];
    const int blk = blockIdx.x;
    const int tid = threadIdx.x;
    if (blk < 6144) {
        int i = blk * 256 + tid;
        float4 v = x4[i];
        uint2 o;
        o.x = cvt_pk_bf16(v.x, v.y);
        o.y = cvt_pk_bf16(v.z, v.w);
        *(uint2*)&xbf4[i] = o;
        return;
    }
    const float* src; unsigned short* dst; int R, Cc, c0, r0;
    if (blk < 7872) {
        int idx = blk - 6144;           // w_attn: tiles (72 c, 24 r)
        src = w_attn; dst = waT; R = 768; Cc = 2304;
        c0 = (idx % 72) * 32; r0 = (idx / 72) * 32;
    } else {
        int idx = blk - 7872;           // w_proj: tiles (24 c, 24 r)
        src = w_proj; dst = wpT; R = 768; Cc = 768;
        c0 = (idx % 24) * 32; r0 = (idx / 24) * 32;
    }
    const int tx = tid & 31, ty = tid >> 5;
#pragma unroll
    for (int i = 0; i < 4; i++)
        tile[ty + i * 8][tx] = src[(size_t)(r0 + ty + i * 8) * Cc + c0 + tx];
    __syncthreads();
#pragma unroll
    for (int i = 0; i < 4; i++)
        dst[(size_t)(c0 + ty + i * 8) * R + r0 + tx] = f2bf(tile[tx][ty + i * 8]);
}

// ---------------------------------------------------------------------------
// qkv core (champion, ~55 us): 128x128 tile, 4 waves, 2-phase double buffer,
// counted vmcnt: stage(t+1) -> s_waitcnt vmcnt(8) (retires exactly tile-t's
// 8 loads, FIFO; t+1's 8 stay in flight) -> s_barrier -> compute(t) ->
// s_barrier. XOR-granule swizzle (0 bank conflicts), 64 KB LDS, 2 blocks/CU.
// R8 lesson: BK=32 (24 steps) and BN=256 both regress — this tiling is the
// floor for the 2-phase structure.
// ---------------------------------------------------------------------------
__device__ __forceinline__ void stage128(
    const unsigned short* __restrict__ A, const unsigned short* __restrict__ Bt,
    unsigned short* As, unsigned short* Bs, int mBase, int nBase, int kt,
    int wv, int lane)
{
#pragma unroll
    for (int i = 0; i < 4; i++) {
        int cbase = i * 256 + wv * 64;       // wave-uniform chunk base
        int ci = cbase + lane;               // 16B chunk 0..1023
        int r = ci >> 3;
        int koff = (((ci & 7) ^ (r & 7)) << 3);   // swizzled granule
        __builtin_amdgcn_global_load_lds(
            AS1C(A + (size_t)(mBase + r) * 768 + kt + koff),
            AS3(As + cbase * 8), 16, 0, 0);
        __builtin_amdgcn_global_load_lds(
            AS1C(Bt + (size_t)(nBase + r) * 768 + kt + koff),
            AS3(Bs + cbase * 8), 16, 0, 0);
    }
}   // 8 global_load_lds per thread per K-step

__device__ __forceinline__ void gemm128_core(
    const unsigned short* __restrict__ A, const unsigned short* __restrict__ Bt,
    unsigned short (*As)[128 * 64], unsigned short (*Bs)[128 * 64],
    f32x4_t acc[4][4], int mBase, int nBase)
{
    const int tid  = threadIdx.x;
    const int lane = tid & 63;
    const int wv   = tid >> 6;
    const int quad = lane >> 4;
    const int l16  = lane & 15;
    const int wm   = (wv >> 1) * 64;
    const int wn   = (wv & 1) * 64;

    f32x4_t zero = {0.f, 0.f, 0.f, 0.f};
#pragma unroll
    for (int tm = 0; tm < 4; tm++)
#pragma unroll
        for (int tn = 0; tn < 4; tn++)
            acc[tm][tn] = zero;

    stage128(A, Bt, As[0], Bs[0], mBase, nBase, 0, wv, lane);
    __syncthreads();                         // tile0 resident (drain ok here)

    for (int kt = 0; kt < 12; kt++) {
        const int cur = kt & 1;
        if (kt < 11)                          // issue t+1 loads (stay in flight)
            stage128(A, Bt, As[cur ^ 1], Bs[cur ^ 1], mBase, nBase,
                     (kt + 1) * 64, wv, lane);
        if (kt < 11)
            asm volatile("s_waitcnt vmcnt(8)" ::: "memory");
        else
            asm volatile("s_waitcnt vmcnt(0)" ::: "memory");
        __builtin_amdgcn_s_barrier();        // all waves: tile t fully in LDS
        asm volatile("" ::: "memory");
        const unsigned short* Ac = As[cur];
        const unsigned short* Bc = Bs[cur];
#pragma unroll
        for (int ks = 0; ks < 2; ks++) {
            bf16x8_t af[4], bfv[4];
#pragma unroll
            for (int tm = 0; tm < 4; tm++)
                af[tm] = *(const bf16x8_t*)(Ac + (wm + tm * 16 + l16) * 64 +
                                            (((ks * 4 + quad) ^ (l16 & 7)) << 3));
#pragma unroll
            for (int tn = 0; tn < 4; tn++)
                bfv[tn] = *(const bf16x8_t*)(Bc + (wn + tn * 16 + l16) * 64 +
                                             (((ks * 4 + quad) ^ (l16 & 7)) << 3));
#pragma unroll
            for (int tm = 0; tm < 4; tm++)
#pragma unroll
                for (int tn = 0; tn < 4; tn++)
                    acc[tm][tn] = __builtin_amdgcn_mfma_f32_16x16x32_bf16(
                        af[tm], bfv[tn], acc[tm][tn], 0, 0, 0);
        }
        asm volatile("" ::: "memory");
        __builtin_amdgcn_s_barrier();        // WAR fence: buf[cur] free for t+2
    }
}

// GEMM1: qkv = x @ w_attn + b_attn. 1D grid 1152, XCD-sliced.
__global__ __launch_bounds__(256) void gemm_qkv(
    const unsigned short* __restrict__ x, const unsigned short* __restrict__ waT,
    const float* __restrict__ b_attn,
    unsigned short* __restrict__ qbuf, unsigned short* __restrict__ kbuf,
    unsigned short* __restrict__ vbuf)
{
    __shared__ __align__(16) unsigned short As[2][128 * 64];   // 32 KB
    __shared__ __align__(16) unsigned short Bs[2][128 * 64];   // 32 KB
    f32x4_t acc[4][4];
    const int lid = blockIdx.x;
    const int xcd = lid & 7;
    const int j = lid >> 3;                 // 0..143
    const int mTile = xcd * 8 + (j & 7);    // 0..63
    const int nTile = j >> 3;               // 0..17
    const int mBase = mTile * 128;
    const int nBase = nTile * 128;
    gemm128_core(x, waT, As, Bs, acc, mBase, nBase);

    const int tid = threadIdx.x;
    const int lane = tid & 63, wv = tid >> 6;
    const int quad = lane >> 4, l16 = lane & 15;
    const int wm = (wv >> 1) * 64, wn = (wv & 1) * 64;
    const int part = nTile / 6;             // 0=q 1=k 2=v (block-uniform)

#pragma unroll
    for (int tn = 0; tn < 4; tn++) {
        int n = nBase + wn + tn * 16 + l16;     // 0..2303
        float bv = b_attn[n];
        int f = n - part * 768;
        int hh = f >> 6, d = f & 63;
        if (part == 2) {
#pragma unroll
            for (int tm = 0; tm < 4; tm++) {
                int t0 = mBase + wm + tm * 16 + quad * 4;   // 4-aligned, no b-crossing
                int bb = t0 >> 10, tt = t0 & 1023;
                uint2 pk2;
                pk2.x = cvt_pk_bf16(acc[tm][tn][0] + bv, acc[tm][tn][1] + bv);
                pk2.y = cvt_pk_bf16(acc[tm][tn][2] + bv, acc[tm][tn][3] + bv);
                *(uint2*)(vbuf + ((size_t)(bb * N_HEAD + hh) * HDIM + d) * SEQ_T + tt) = pk2;
            }
        } else {
            const float scale = (part == 0) ? L2E : 1.f;
            unsigned short* dst = (part == 0) ? qbuf : kbuf;
#pragma unroll
            for (int tm = 0; tm < 4; tm++) {
#pragma unroll
                for (int i = 0; i < 4; i++) {
                    int row = mBase + wm + tm * 16 + quad * 4 + i;
                    int bb = row >> 10, tt = row & 1023;
                    dst[((size_t)(bb * N_HEAD + hh) * SEQ_T + tt) * HDIM + d] =
                        f2bf((acc[tm][tn][i] + bv) * scale);
                }
            }
        }
    }
}

// ---------------------------------------------------------------------------
// proj core (R5-verified): 8-wave 128x256 tile, triple-buffered LDS (144 KB),
// depth-2 prefetch, counted vmcnt across raw s_barrier. proj-only.
// ---------------------------------------------------------------------------
#define KTILES 12               // 768 / 64
#define ASTRIDE (128 * 64)      // halfwords per A K-tile buffer
#define BSTRIDE (256 * 64)      // halfwords per B K-tile buffer

__device__ __forceinline__ void stage_tile(
    const unsigned short* __restrict__ A, const unsigned short* __restrict__ Bt,
    unsigned short* As, unsigned short* Bs, int mBase, int nBase, int kt,
    int wv, int lane)
{
#pragma unroll
    for (int i = 0; i < 2; i++) {
        int cbase = i * 512 + wv * 64;       // wave-uniform chunk base
        int ci = cbase + lane;
        int r = ci >> 3;
        int koff = (((ci & 7) ^ (r & 7)) << 3);
        __builtin_amdgcn_global_load_lds(
            AS1C(A + (size_t)(mBase + r) * 768 + kt + koff),
            AS3(As + cbase * 8), 16, 0, 0);
    }
#pragma unroll
    for (int i = 0; i < 4; i++) {
        int cbase = i * 512 + wv * 64;
        int ci = cbase + lane;
        int r = ci >> 3;
        int koff = (((ci & 7) ^ (r & 7)) << 3);
        __builtin_amdgcn_global_load_lds(
            AS1C(Bt + (size_t)(nBase + r) * 768 + kt + koff),
            AS3(Bs + cbase * 8), 16, 0, 0);
    }
}   // 6 global_load_lds per thread per K-tile

__device__ __forceinline__ void compute_tile(
    const unsigned short* As, const unsigned short* Bs,
    f32x4_t acc[4][4], int wm, int wn, int quad, int l16)
{
#pragma unroll
    for (int ks = 0; ks < 2; ks++) {
        bf16x8_t af[4], bfv[4];
#pragma unroll
        for (int tm = 0; tm < 4; tm++)
            af[tm] = *(const bf16x8_t*)(As + (wm + tm * 16 + l16) * 64 +
                                        (((ks * 4 + quad) ^ (l16 & 7)) << 3));
#pragma unroll
        for (int tn = 0; tn < 4; tn++)
            bfv[tn] = *(const bf16x8_t*)(Bs + (wn + tn * 16 + l16) * 64 +
                                         (((ks * 4 + quad) ^ (l16 & 7)) << 3));
#pragma unroll
        for (int tm = 0; tm < 4; tm++)
#pragma unroll
            for (int tn = 0; tn < 4; tn++)
                acc[tm][tn] = __builtin_amdgcn_mfma_f32_16x16x32_bf16(
                    af[tm], bfv[tn], acc[tm][tn], 0, 0, 0);
    }
}

__device__ __forceinline__ void gemm_core8(
    const unsigned short* __restrict__ A, const unsigned short* __restrict__ Bt,
    unsigned short* As, unsigned short* Bs, f32x4_t acc[4][4],
    int mBase, int nBase)
{
    const int tid  = threadIdx.x;
    const int lane = tid & 63;
    const int wv   = tid >> 6;          // 0..7
    const int quad = lane >> 4;
    const int l16  = lane & 15;
    const int wm   = (wv >> 2) * 64;    // 2 M-waves
    const int wn   = (wv & 3) * 64;     // 4 N-waves

    f32x4_t zero = {0.f, 0.f, 0.f, 0.f};
#pragma unroll
    for (int tm = 0; tm < 4; tm++)
#pragma unroll
        for (int tn = 0; tn < 4; tn++)
            acc[tm][tn] = zero;

    stage_tile(A, Bt, As + 0 * ASTRIDE, Bs + 0 * BSTRIDE, mBase, nBase, 0, wv, lane);
    stage_tile(A, Bt, As + 1 * ASTRIDE, Bs + 1 * BSTRIDE, mBase, nBase, 64, wv, lane);

#pragma unroll
    for (int t = 0; t < KTILES; t++) {
        if (t + 2 < KTILES) {
            const int nb = (t + 2) % 3;
            stage_tile(A, Bt, As + nb * ASTRIDE, Bs + nb * BSTRIDE,
                       mBase, nBase, (t + 2) * 64, wv, lane);
        }
        if (t + 2 < KTILES)
            asm volatile("s_waitcnt vmcnt(12)" ::: "memory");
        else if (t + 1 < KTILES)
            asm volatile("s_waitcnt vmcnt(6)" ::: "memory");
        else
            asm volatile("s_waitcnt vmcnt(0)" ::: "memory");
        __builtin_amdgcn_s_barrier();           // raw barrier: no vmcnt drain
        asm volatile("" ::: "memory");
        const int cb = t % 3;
        compute_tile(As + cb * ASTRIDE, Bs + cb * BSTRIDE, acc, wm, wn, quad, l16);
        asm volatile("" ::: "memory");
        __builtin_amdgcn_s_barrier();           // all waves done reading buf t%3
    }
}

// mask + exp2 + l-accumulate + pack to bf16 pairs (pure VALU, no memory ops).
__device__ __forceinline__ void mask_exp_pack(
    f32x4_t s[4], int diag, int qloc, int quad,
    float& lsum, unsigned int u[4][2])
{
    if (diag) {
#pragma unroll
        for (int c = 0; c < 4; c++)
#pragma unroll
            for (int i = 0; i < 4; i++)
                if (c * 16 + quad * 4 + i > qloc) s[c][i] = -1e30f;
    }
    float p[4][4];
#pragma unroll
    for (int c = 0; c < 4; c++)
#pragma unroll
        for (int i = 0; i < 4; i++)
            p[c][i] = __builtin_amdgcn_exp2f(s[c][i]);
#pragma unroll
    for (int c = 0; c < 4; c++)
        lsum += (p[c][0] + p[c][1]) + (p[c][2] + p[c][3]);
#pragma unroll
    for (int c = 0; c < 4; c++)
#pragma unroll
        for (int i2 = 0; i2 < 2; i2++)
            u[c][i2] = cvt_pk_bf16(p[c][2 * i2], p[c][2 * i2 + 1]);
}

__device__ __forceinline__ void p_write(
    unsigned short* pw, const unsigned int u[4][2], int quad, int l16)
{
#pragma unroll
    for (int c = 0; c < 4; c++)
#pragma unroll
        for (int i2 = 0; i2 < 2; i2++) {
            int g = c * 2 + (quad >> 1);
            *(unsigned int*)(pw + l16 * 64 + ((g ^ (l16 & 7)) << 3) +
                             4 * (quad & 1) + 2 * i2) = u[c][i2];
        }
}

// Fused causal attention (R6/R7 champion structure; R8's dual-Psh reverted —
// it cost ~3.5 us). R9: T5 s_setprio(1) around MFMA clusters — 3 independent
// blocks/CU give wave role-diversity (m191 regime: attn +4-7%).
__global__ __launch_bounds__(256, 3) void attn_fused(
    const unsigned short* __restrict__ qb, const unsigned short* __restrict__ kb,
    const unsigned short* __restrict__ vb, unsigned short* __restrict__ attb)
{
    __shared__ __align__(16) unsigned short Kbuf[2][64 * 64];
    __shared__ __align__(16) unsigned short Vbuf[2][64 * 64];   // V^T tiles [d][s]
    __shared__ __align__(16) unsigned short Psh[4][16 * 64];

    const int bhx = blockIdx.x;     // 0..95
    const int t   = blockIdx.y;     // 0..7; tiles t and 15-t
    const int h = bhx % N_HEAD;
    const int b = bhx / N_HEAD;
    const int tid = threadIdx.x;
    const int lane = tid & 63, wv = tid >> 6;
    const int quad = lane >> 4, l16 = lane & 15;
    const int tB = 15 - t, kmax = 15 - t;
    const int qloc = wv * 16 + l16;

    const size_t bh = (size_t)(b * N_HEAD + h);
    const unsigned short* kbase = kb + bh * SEQ_T * HDIM;
    const unsigned short* vbase = vb + bh * HDIM * SEQ_T;
    const unsigned short* qpt   = qb + bh * SEQ_T * HDIM;

    const int j0 = wv * 128 + lane, j1 = j0 + 64;
    const int r0 = j0 >> 3, g0 = (j0 & 7) ^ (r0 & 7);
    const int r1 = j1 >> 3, g1 = (j1 & 7) ^ (r1 & 7);
    const int rgK0 = r0 * 64 + g0 * 8,   rgK1 = r1 * 64 + g1 * 8;
    const int rgV0 = r0 * 1024 + g0 * 8, rgV1 = r1 * 1024 + g1 * 8;
    const int ldsc0 = (wv * 128) * 8, ldsc1 = (wv * 128 + 64) * 8;  // wave-uniform

    bf16x8_t qfA[2], qfB[2];
    {
        const unsigned short* qa  = qpt + (size_t)(t * 64 + qloc) * HDIM;
        const unsigned short* qbp = qpt + (size_t)(tB * 64 + qloc) * HDIM;
#pragma unroll
        for (int kc = 0; kc < 2; kc++) {
            qfA[kc] = *(const bf16x8_t*)(qa + kc * 32 + quad * 8);
            qfB[kc] = *(const bf16x8_t*)(qbp + kc * 32 + quad * 8);
        }
    }

    f32x4_t zero = {0.f, 0.f, 0.f, 0.f};
    f32x4_t oA[4], oB[4];
#pragma unroll
    for (int c = 0; c < 4; c++) { oA[c] = zero; oB[c] = zero; }
    float lA = 0.f, lB = 0.f;

    __builtin_amdgcn_global_load_lds(AS1C(kbase + rgK0), AS3(&Kbuf[0][0] + ldsc0), 16, 0, 0);
    __builtin_amdgcn_global_load_lds(AS1C(kbase + rgK1), AS3(&Kbuf[0][0] + ldsc1), 16, 0, 0);
    __builtin_amdgcn_global_load_lds(AS1C(vbase + rgV0), AS3(&Vbuf[0][0] + ldsc0), 16, 0, 0);
    __builtin_amdgcn_global_load_lds(AS1C(vbase + rgV1), AS3(&Vbuf[0][0] + ldsc1), 16, 0, 0);
    __syncthreads();

    for (int kt = 0; kt <= kmax; kt++) {
        const int cur = kt & 1, nxt = cur ^ 1;
        if (kt < kmax) {
            const unsigned short* kp = kbase + (kt + 1) * 4096;
            const unsigned short* vp = vbase + (kt + 1) * 64;
            __builtin_amdgcn_global_load_lds(AS1C(kp + rgK0), AS3(&Kbuf[nxt][0] + ldsc0), 16, 0, 0);
            __builtin_amdgcn_global_load_lds(AS1C(kp + rgK1), AS3(&Kbuf[nxt][0] + ldsc1), 16, 0, 0);
            __builtin_amdgcn_global_load_lds(AS1C(vp + rgV0), AS3(&Vbuf[nxt][0] + ldsc0), 16, 0, 0);
            __builtin_amdgcn_global_load_lds(AS1C(vp + rgV1), AS3(&Vbuf[nxt][0] + ldsc1), 16, 0, 0);
        }

        const unsigned short* Kc = &Kbuf[cur][0];
        const unsigned short* Vc = &Vbuf[cur][0];
        const int doA = (kt <= t);

        bf16x8_t vf[4][2];
#pragma unroll
        for (int nc = 0; nc < 4; nc++)
#pragma unroll
            for (int kc = 0; kc < 2; kc++)
                vf[nc][kc] = *(const bf16x8_t*)(Vc + (nc * 16 + l16) * 64 +
                                                (((kc * 4 + quad) ^ (l16 & 7)) << 3));

        f32x4_t sB[4], sA[4];
        __builtin_amdgcn_s_setprio(1);
#pragma unroll
        for (int c = 0; c < 4; c++) {
            bf16x8_t kf0 = *(const bf16x8_t*)(Kc + (c * 16 + l16) * 64 +
                                              ((quad ^ (l16 & 7)) << 3));
            bf16x8_t kf1 = *(const bf16x8_t*)(Kc + (c * 16 + l16) * 64 +
                                              (((4 + quad) ^ (l16 & 7)) << 3));
            sB[c] = __builtin_amdgcn_mfma_f32_16x16x32_bf16(kf0, qfB[0], zero, 0, 0, 0);
            sB[c] = __builtin_amdgcn_mfma_f32_16x16x32_bf16(kf1, qfB[1], sB[c], 0, 0, 0);
            if (doA) {
                sA[c] = __builtin_amdgcn_mfma_f32_16x16x32_bf16(kf0, qfA[0], zero, 0, 0, 0);
                sA[c] = __builtin_amdgcn_mfma_f32_16x16x32_bf16(kf1, qfA[1], sA[c], 0, 0, 0);
            }
        }
        __builtin_amdgcn_s_setprio(0);

        unsigned short* pw = &Psh[wv][0];
        unsigned int uB[4][2], uA[4][2];

        mask_exp_pack(sB, kt == tB, qloc, quad, lB, uB);
        __asm__ __volatile__("" ::: "memory");
        p_write(pw, uB, quad, l16);                    // P_B -> LDS
        if (doA)
            mask_exp_pack(sA, kt == t, qloc, quad, lA, uA);  // VALU hides P_B drain
        __asm__ __volatile__("" ::: "memory");
        bf16x8_t pfB[2];
#pragma unroll
        for (int kc = 0; kc < 2; kc++)
            pfB[kc] = *(const bf16x8_t*)(pw + l16 * 64 + (((kc * 4 + quad) ^ (l16 & 7)) << 3));
        __asm__ __volatile__("" ::: "memory");         // keep P_A writes after P_B reads
        __builtin_amdgcn_s_setprio(1);
#pragma unroll
        for (int kc = 0; kc < 2; kc++)
#pragma unroll
            for (int nc = 0; nc < 4; nc++)
                oB[nc] = __builtin_amdgcn_mfma_f32_16x16x32_bf16(pfB[kc], vf[nc][kc], oB[nc], 0, 0, 0);
        __builtin_amdgcn_s_setprio(0);
        if (doA) {
            p_write(pw, uA, quad, l16);                // P_A -> LDS (PV_B MFMAs overlap)
            __asm__ __volatile__("" ::: "memory");
            bf16x8_t pfA[2];
#pragma unroll
            for (int kc = 0; kc < 2; kc++)
                pfA[kc] = *(const bf16x8_t*)(pw + l16 * 64 + (((kc * 4 + quad) ^ (l16 & 7)) << 3));
            __builtin_amdgcn_s_setprio(1);
#pragma unroll
            for (int kc = 0; kc < 2; kc++)
#pragma unroll
                for (int nc = 0; nc < 4; nc++)
                    oA[nc] = __builtin_amdgcn_mfma_f32_16x16x32_bf16(pfA[kc], vf[nc][kc], oA[nc], 0, 0, 0);
            __builtin_amdgcn_s_setprio(0);
        }
        __syncthreads();
    }

    lA += __shfl_xor(lA, 16); lA += __shfl_xor(lA, 32);
    lB += __shfl_xor(lB, 16); lB += __shfl_xor(lB, 32);
    float invA = 1.f / lA, invB = 1.f / lB;
    float iA[4], iB[4];
#pragma unroll
    for (int i = 0; i < 4; i++) {
        iA[i] = __shfl(invA, quad * 4 + i);
        iB[i] = __shfl(invB, quad * 4 + i);
    }

#pragma unroll
    for (int nc = 0; nc < 4; nc++)
#pragma unroll
        for (int i = 0; i < 4; i++) {
            int rowA = t * 64 + wv * 16 + quad * 4 + i;
            int rowB = tB * 64 + wv * 16 + quad * 4 + i;
            int col = h * HDIM + nc * 16 + l16;
            attb[((size_t)b * SEQ_T + rowA) * CDIM + col] = f2bf(oA[nc][i] * iA[i]);
            attb[((size_t)b * SEQ_T + rowB) * CDIM + col] = f2bf(oB[nc][i] * iB[i]);
        }
}

// GEMM2: out(fp32) = att @ w_proj + b_proj. R5-verified config: BM=128 BN=256
// -> grid 64*3=192 (192%8==0, XCD-sliced), 512 thr, 144 KB LDS triple-buffer.
__global__ __launch_bounds__(512) void gemm_proj(
    const unsigned short* __restrict__ attb, const unsigned short* __restrict__ wpT,
    const float* __restrict__ b_proj, float* __restrict__ out)
{
    __shared__ __align__(16) unsigned short As[3 * ASTRIDE];   // 48 KB
    __shared__ __align__(16) unsigned short Bs[3 * BSTRIDE];   // 96 KB
    f32x4_t acc[4][4];
    const int lid = blockIdx.x;             // 0..191
    const int xcd = lid & 7;
    const int j = lid >> 3;                 // 0..23
    const int mTile = xcd * 8 + (j & 7);    // 0..63
    const int nTile = j >> 3;               // 0..2
    const int mBase = mTile * 128;
    const int nBase = nTile * 256;
    gemm_core8(attb, wpT, As, Bs, acc, mBase, nBase);

    const int tid  = threadIdx.x;
    const int lane = tid & 63;
    const int wv   = tid >> 6;
    const int quad = lane >> 4;
    const int l16  = lane & 15;
    const int wm   = (wv >> 2) * 64;
    const int wn   = (wv & 3) * 64;

#pragma unroll
    for (int tn = 0; tn < 4; tn++) {
        int n = nBase + wn + tn * 16 + l16;
        float bv = b_proj[n];
#pragma unroll
        for (int tm = 0; tm < 4; tm++)
#pragma unroll
            for (int i = 0; i < 4; i++) {
                int row = mBase + wm + tm * 16 + quad * 4 + i;
                out[(size_t)row * CDIM + n] = acc[tm][tn][i] + bv;
            }
    }
}

extern "C" void kernel_launch(void* const* d_in, const int* in_sizes, int n_in,
                              void* d_out, int out_size, void* d_ws, size_t ws_size,
                              hipStream_t stream) {
    const float* x      = (const float*)d_in[0];  // [8,1024,768] fp32
    const float* w_attn = (const float*)d_in[1];  // [768,2304]   fp32
    const float* b_attn = (const float*)d_in[2];  // [2304]       fp32
    const float* w_proj = (const float*)d_in[3];  // [768,768]    fp32
    const float* b_proj = (const float*)d_in[4];  // [768]        fp32
    float* out = (float*)d_out;                   // [8,1024,768] fp32

    unsigned short* ws   = (unsigned short*)d_ws;
    unsigned short* waT  = ws;                    // [2304][768] bf16
    unsigned short* wpT  = waT + 1769472;         // [768][768]  bf16
    unsigned short* xbf  = wpT + 589824;          // [8192][768] bf16
    unsigned short* qbuf = xbf + 6291456;         // [B,H,T,D] (log2e-scaled)
    unsigned short* kbuf = qbuf + 6291456;        // [B,H,T,D]
    unsigned short* vbuf = kbuf + 6291456;        // [B,H,D,T]
    unsigned short* attb = vbuf + 6291456;        // [B,T,C]
    // ws use: 67,633,152 bytes

    prep<<<dim3(8448), 256, 0, stream>>>((const float4*)x, (ushort4*)xbf,
                                         w_attn, waT, w_proj, wpT);
    gemm_qkv<<<dim3(1152), 256, 0, stream>>>(xbf, waT, b_attn, qbuf, kbuf, vbuf);
    attn_fused<<<dim3(96, 8), 256, 0, stream>>>(qbuf, kbuf, vbuf, attb);
    gemm_proj<<<dim3(192), 512, 0, stream>>>(attb, wpT, b_proj, out);
}